// Round 3
// baseline (642.211 us; speedup 1.0000x reference)
//
#include <hip/hip_runtime.h>

// BlurPool3d: x (4,64,32,112,112) f32, replicate-pad 1, depthwise 3x3x3
// binomial [1,2,1]/4 separable blur, stride 2 -> out (4,64,16,56,56) f32.
// HBM floor: 411 MB read + 51 MB write ~= 73 us at 6.3 TB/s achievable.
//
// R2: thread = (nc, od-half, oh, ow8). 8 outputs along W (17-float window,
// 4 aligned float4 + 1 clamped scalar per row) x 8 outputs along D via a
// sliding-plane window: consecutive od share plane 2od+1, so its H-sum is
// computed once and carried in registers. 17 planes read per thread for 8
// output planes (vs 24 plane-visits without sliding). 54 B of load requests
// per output (ideal 32). Stores: 2x float4 per od, lanes tile output rows
// contiguously.

#define IN_D 32
#define IN_H 112
#define IN_W 112
#define OUT_D 16
#define OUT_H 56
#define OUT_W 56
#define PLANE (IN_H * IN_W)
#define OW8 7           // 56/8 W-tiles
#define ODH 2           // two D-halves of 8 od each

// H-reduced W-conv for one input plane: hs[j] = sum_kh wh[kh] * wconv(row ih_kh)[j]
__device__ __forceinline__ void plane_hsum(const float* __restrict__ pd,
                                           int ih0, int ih1, int ih2,
                                           int iwbase, int iwl, float hs[8])
{
#pragma unroll
    for (int j = 0; j < 8; ++j) hs[j] = 0.f;
    const int ihs[3] = {ih0, ih1, ih2};
#pragma unroll
    for (int kh = 0; kh < 3; ++kh) {
        const float* row = pd + ihs[kh] * IN_W;
        float4 r0 = *(const float4*)(row + iwbase);
        float4 r1 = *(const float4*)(row + iwbase + 4);
        float4 r2 = *(const float4*)(row + iwbase + 8);
        float4 r3 = *(const float4*)(row + iwbase + 12);
        float left = row[iwl];
        float wt = (kh == 1) ? 2.0f : 1.0f;
        // output j uses e[2j],e[2j+1],e[2j+2] where e[k] = x[iwbase-1+k]
        hs[0] = fmaf(wt, left + 2.f * r0.x + r0.y, hs[0]);
        hs[1] = fmaf(wt, r0.y + 2.f * r0.z + r0.w, hs[1]);
        hs[2] = fmaf(wt, r0.w + 2.f * r1.x + r1.y, hs[2]);
        hs[3] = fmaf(wt, r1.y + 2.f * r1.z + r1.w, hs[3]);
        hs[4] = fmaf(wt, r1.w + 2.f * r2.x + r2.y, hs[4]);
        hs[5] = fmaf(wt, r2.y + 2.f * r2.z + r2.w, hs[5]);
        hs[6] = fmaf(wt, r2.w + 2.f * r3.x + r3.y, hs[6]);
        hs[7] = fmaf(wt, r3.y + 2.f * r3.z + r3.w, hs[7]);
    }
}

__global__ __launch_bounds__(256) void blurpool3d_kernel(
    const float* __restrict__ x, float* __restrict__ out)
{
    int idx = blockIdx.x * 256 + threadIdx.x;
    // idx -> (nc, odh, oh, ow8); total = 256*2*56*7 = 200704 (exact grid)
    int t    = idx;
    int ow8  = t % OW8;  t /= OW8;
    int oh   = t % OUT_H; t /= OUT_H;
    int odh  = t % ODH;
    int nc   = t / ODH;              // n*C + c, 0..255

    int iwbase = ow8 * 16;
    int iwl    = max(iwbase - 1, 0);
    int ih1 = 2 * oh;
    int ih0 = max(ih1 - 1, 0);
    int ih2 = ih1 + 1;
    int od0 = odh * 8;

    const float* p = x + (size_t)nc * (IN_D * PLANE);

    // seed: plane id = 2*od0 - 1 (clamped to 0 for od0==0, matching replicate pad)
    float hprev[8];
    {
        int id = max(2 * od0 - 1, 0);
        plane_hsum(p + (size_t)id * PLANE, ih0, ih1, ih2, iwbase, iwl, hprev);
    }

    size_t obase = (((size_t)nc * OUT_D + od0) * OUT_H + oh) * OUT_W + ow8 * 8;

#pragma unroll
    for (int k = 0; k < 8; ++k) {
        int od = od0 + k;
        float h1[8], h2[8];
        plane_hsum(p + (size_t)(2 * od) * PLANE,     ih0, ih1, ih2, iwbase, iwl, h1);
        plane_hsum(p + (size_t)(2 * od + 1) * PLANE, ih0, ih1, ih2, iwbase, iwl, h2);

        float4 o0, o1;
        o0.x = (hprev[0] + 2.f * h1[0] + h2[0]) * (1.f / 64.f);
        o0.y = (hprev[1] + 2.f * h1[1] + h2[1]) * (1.f / 64.f);
        o0.z = (hprev[2] + 2.f * h1[2] + h2[2]) * (1.f / 64.f);
        o0.w = (hprev[3] + 2.f * h1[3] + h2[3]) * (1.f / 64.f);
        o1.x = (hprev[4] + 2.f * h1[4] + h2[4]) * (1.f / 64.f);
        o1.y = (hprev[5] + 2.f * h1[5] + h2[5]) * (1.f / 64.f);
        o1.z = (hprev[6] + 2.f * h1[6] + h2[6]) * (1.f / 64.f);
        o1.w = (hprev[7] + 2.f * h1[7] + h2[7]) * (1.f / 64.f);

        float* o = out + obase + (size_t)k * (OUT_H * OUT_W);
        *(float4*)o = o0;
        *(float4*)(o + 4) = o1;

#pragma unroll
        for (int j = 0; j < 8; ++j) hprev[j] = h2[j];
    }
}

extern "C" void kernel_launch(void* const* d_in, const int* in_sizes, int n_in,
                              void* d_out, int out_size, void* d_ws, size_t ws_size,
                              hipStream_t stream)
{
    const float* x = (const float*)d_in[0];
    float* out = (float*)d_out;
    // 256 nc * 2 odh * 56 oh * 7 ow8 = 200704 threads = 784 blocks (exact)
    blurpool3d_kernel<<<784, 256, 0, stream>>>(x, out);
}